// Round 4
// baseline (247.598 us; speedup 1.0000x reference)
//
#include <hip/hip_runtime.h>

// EFDM loss — reduced form:
//   pos_sum[b]  = sum over (a,p,c,j) of (sortT[a,p,b,c][j] - sortS[a,p,b,c][j])^2
//   neg_sum[b]  = sum over (a,p,k,c,j) of (sortT[a,p,b,c][j] - sortS[a,p,nb(b,k),c][j])^2
//   out = sum_b pos_sum[b]/neg_sum[b]          (the 1/(C*N) mean factors cancel)
//
// Register bitonic sort: 32 elems/thread, 128 threads/row (2 waves).
//  - sign-negation trick: all cross/tail compares become static min/max + cndmask
//  - stages k<=32 fully in-register; lane-xor 1/2 via DPP quad_perm;
//    4/8 via ds_swizzle; 16/32 via paired v_permlane16/32_swap;
//    thread-xor 64 (the ONLY cross-wave pass) via LDS — one barrier per sort.

constexpr int N    = 4096;
constexpr int NTH  = 128;
constexpr int E    = 32;    // elements per thread
constexpr int CDIM = 128;
constexpr int BDIM = 4;
constexpr int KNEG = 2;
constexpr int ROWS = 4096;
constexpr int HALF = 2048;
constexpr int LSTR = 36;    // LDS floats per thread row: 144B, 16B-aligned, <=2-way conflict

__device__ inline unsigned fasu(float x) { return __float_as_uint(x); }
__device__ inline float    usaf(unsigned x) { return __uint_as_float(x); }

__device__ inline void cswap_asc(float& a, float& b) {
  const float lo = fminf(a, b), hi = fmaxf(a, b);
  a = lo; b = hi;
}

// stages k<=16: direction static from local index m
template<int K, int J>
__device__ inline void local_pass(float v[E]) {
  #pragma unroll
  for (int m = 0; m < E; ++m)
    if ((m & J) == 0) {
      if ((m & K) == 0) cswap_asc(v[m], v[m ^ J]);
      else              cswap_asc(v[m ^ J], v[m]);
    }
}

// ascending in-register tail: j = J, J/2, .., 1
template<int J>
__device__ inline void reg_passes_asc(float v[E]) {
  if constexpr (J >= 1) {
    #pragma unroll
    for (int m = 0; m < E; ++m)
      if ((m & J) == 0) cswap_asc(v[m], v[m ^ J]);
    reg_passes_asc<(J >> 1)>(v);
  }
}

// DPP quad_perm exchange: 0xB1 = [1,0,3,2] = xor1, 0x4E = [2,3,0,1] = xor2
template<int CTRL>
__device__ inline float dpp_x(float x) {
  const int s = (int)fasu(x);
  return usaf((unsigned)__builtin_amdgcn_update_dpp(s, s, CTRL, 0xF, 0xF, false));
}

// lane-xor TM in {1,2,4,8}: per-lane keep-min = ((t&TM)==0)
template<int TM>
__device__ inline void pass_small(float v[E], int t) {
  const bool km = ((t & TM) == 0);
  #pragma unroll
  for (int m = 0; m < E; ++m) {
    float o;
    if constexpr (TM == 1)      o = dpp_x<0xB1>(v[m]);
    else if constexpr (TM == 2) o = dpp_x<0x4E>(v[m]);
    else if constexpr (TM == 4)
      o = usaf((unsigned)__builtin_amdgcn_ds_swizzle((int)fasu(v[m]), 0x101F));
    else
      o = usaf((unsigned)__builtin_amdgcn_ds_swizzle((int)fasu(v[m]), 0x201F));
    v[m] = km ? fminf(v[m], o) : fmaxf(v[m], o);
  }
}

// gfx950 permlane swaps: both operands read AND written.
__device__ inline void swap32(float& a, float& b) {
  asm("v_permlane32_swap_b32 %0, %1" : "+v"(a), "+v"(b));
}
__device__ inline void swap16(float& a, float& b) {
  asm("v_permlane16_swap_b32 %0, %1" : "+v"(a), "+v"(b));
}

// lane-xor 16/32 butterfly on element PAIRs: 2 swaps + min + max -> both results,
// min landing in the (t&TM)==0 lanes.
template<bool IS32>
__device__ inline void pass_perm(float v[E]) {
  #pragma unroll
  for (int m = 0; m < E; m += 2) {
    float a = v[m], b = v[m + 1];
    if constexpr (IS32) swap32(a, b); else swap16(a, b);
    float mn = fminf(a, b);
    float mx = fmaxf(a, b);
    if constexpr (IS32) swap32(mn, mx); else swap16(mn, mx);
    v[m] = mn; v[m + 1] = mx;
  }
}

// thread-xor 64 via LDS (only cross-wave pass); keep decision wave-uniform
__device__ inline void pass_lds64(float v[E], float* buf, int t) {
  float4* wp = (float4*)(buf + t * LSTR);
  #pragma unroll
  for (int q = 0; q < 8; ++q)
    wp[q] = make_float4(v[q*4+0], v[q*4+1], v[q*4+2], v[q*4+3]);
  __syncthreads();
  const float4* rp = (const float4*)(buf + (t ^ 64) * LSTR);
  if (t & 64) {
    #pragma unroll
    for (int q = 0; q < 8; ++q) {
      const float4 x = rp[q];
      v[q*4+0] = fmaxf(v[q*4+0], x.x); v[q*4+1] = fmaxf(v[q*4+1], x.y);
      v[q*4+2] = fmaxf(v[q*4+2], x.z); v[q*4+3] = fmaxf(v[q*4+3], x.w);
    }
  } else {
    #pragma unroll
    for (int q = 0; q < 8; ++q) {
      const float4 x = rp[q];
      v[q*4+0] = fminf(v[q*4+0], x.x); v[q*4+1] = fminf(v[q*4+1], x.y);
      v[q*4+2] = fminf(v[q*4+2], x.z); v[q*4+3] = fminf(v[q*4+3], x.w);
    }
  }
}

template<int K, int J>
__device__ inline void cross_passes(float v[E], float* buf, int t) {
  if constexpr (J >= 32) {
    constexpr int TM = J >> 5;
    if constexpr (TM >= 64)      pass_lds64(v, buf, t);
    else if constexpr (TM == 32) pass_perm<true>(v);
    else if constexpr (TM == 16) pass_perm<false>(v);
    else                         pass_small<TM>(v, t);
    cross_passes<K, (J >> 1)>(v, buf, t);
  }
}

__device__ inline void apply_flip(float v[E], unsigned f) {
  #pragma unroll
  for (int m = 0; m < E; ++m) v[m] = usaf(fasu(v[m]) ^ f);
}

// one bitonic stage of width K (>=32), in sign-flipped space
template<int K>
__device__ inline void stage_n(float v[E], float* buf, int t, unsigned& cur) {
  const unsigned f = (t & (K >> 5)) ? 0x80000000u : 0u;
  apply_flip(v, f ^ cur);
  cur = f;
  cross_passes<K, (K >> 1)>(v, buf, t);
  reg_passes_asc<16>(v);
}

// full ascending sort of 4096 floats: v[32] per thread, i = t*32+m
__device__ inline void sort4096(float v[E], float* buf, int t) {
  local_pass<2, 1>(v);
  local_pass<4, 2>(v);  local_pass<4, 1>(v);
  local_pass<8, 4>(v);  local_pass<8, 2>(v);  local_pass<8, 1>(v);
  local_pass<16, 8>(v); local_pass<16, 4>(v); local_pass<16, 2>(v); local_pass<16, 1>(v);
  unsigned cur = 0;
  stage_n<32>(v, buf, t, cur);
  stage_n<64>(v, buf, t, cur);
  stage_n<128>(v, buf, t, cur);
  stage_n<256>(v, buf, t, cur);
  stage_n<512>(v, buf, t, cur);
  stage_n<1024>(v, buf, t, cur);
  stage_n<2048>(v, buf, t, cur);
  stage_n<4096>(v, buf, t, cur);
  apply_flip(v, cur);   // cur == 0 for all t<128, but keep it general
}

__device__ inline void load32(const float* __restrict__ src, float v[E], int t) {
  const float4* s4 = (const float4*)src;
  #pragma unroll
  for (int q = 0; q < 8; ++q) {
    const float4 x = s4[t * 8 + q];
    v[q*4+0] = x.x; v[q*4+1] = x.y; v[q*4+2] = x.z; v[q*4+3] = x.w;
  }
}

__global__ __launch_bounds__(NTH)
void sort_rows(const float* __restrict__ a0, const float* __restrict__ a1,
               float* __restrict__ out) {
  __shared__ float buf[NTH * LSTR];
  const int t = threadIdx.x;
  const int r = blockIdx.x;
  const float* src = (r < HALF) ? a0 + (size_t)r * N
                                : a1 + (size_t)(r - HALF) * N;
  float v[E];
  load32(src, v, t);
  sort4096(v, buf, t);
  float4* d4 = (float4*)(out + (size_t)r * N);
  #pragma unroll
  for (int q = 0; q < 8; ++q)
    d4[t * 8 + q] = make_float4(v[q*4+0], v[q*4+1], v[q*4+2], v[q*4+3]);
}

__global__ __launch_bounds__(NTH)
void loss_rows(const float* __restrict__ t0, const float* __restrict__ t1,
               const float* __restrict__ Vs, const int* __restrict__ neg_idx,
               double* __restrict__ acc) {
  __shared__ float buf[NTH * LSTR];
  __shared__ float red[2][2];
  const int t = threadIdx.x;
  const int r = blockIdx.x;
  const float* src = (r < HALF) ? t0 + (size_t)r * N
                                : t1 + (size_t)(r - HALF) * N;
  float v[E];
  load32(src, v, t);
  sort4096(v, buf, t);

  // r = ((ap)*B + b)*C + c
  const int c  = r & (CDIM - 1);
  const int b  = (r / CDIM) & (BDIM - 1);
  const int ap = r / (CDIM * BDIM);

  float posp = 0.f, negp = 0.f;
  {
    const float4* vp4 = (const float4*)(Vs + (size_t)r * N);
    #pragma unroll
    for (int q = 0; q < 8; ++q) {
      const float4 x = vp4[t * 8 + q];
      float d0 = v[q*4+0] - x.x, d1 = v[q*4+1] - x.y;
      float d2 = v[q*4+2] - x.z, d3 = v[q*4+3] - x.w;
      posp += d0*d0 + d1*d1 + d2*d2 + d3*d3;
    }
  }
  #pragma unroll
  for (int k = 0; k < KNEG; ++k) {
    const int nb = neg_idx[b * KNEG + k];
    const float4* vn4 = (const float4*)(Vs + ((size_t)(ap * BDIM + nb) * CDIM + c) * N);
    #pragma unroll
    for (int q = 0; q < 8; ++q) {
      const float4 x = vn4[t * 8 + q];
      float d0 = v[q*4+0] - x.x, d1 = v[q*4+1] - x.y;
      float d2 = v[q*4+2] - x.z, d3 = v[q*4+3] - x.w;
      negp += d0*d0 + d1*d1 + d2*d2 + d3*d3;
    }
  }

  #pragma unroll
  for (int off = 32; off > 0; off >>= 1) {
    posp += __shfl_down(posp, off, 64);
    negp += __shfl_down(negp, off, 64);
  }
  const int wid = t >> 6, lane = t & 63;
  if (lane == 0) { red[0][wid] = posp; red[1][wid] = negp; }
  __syncthreads();
  if (t == 0) {
    const float pt = red[0][0] + red[0][1];
    const float nt = red[1][0] + red[1][1];
    atomicAdd(&acc[b], (double)pt);
    atomicAdd(&acc[BDIM + b], (double)nt);
  }
}

__global__ void finalize(const double* __restrict__ acc, float* __restrict__ out) {
  if (threadIdx.x == 0 && blockIdx.x == 0) {
    double s = 0.0;
    for (int b = 0; b < BDIM; ++b) s += acc[b] / acc[BDIM + b];
    out[0] = (float)s;
  }
}

extern "C" void kernel_launch(void* const* d_in, const int* in_sizes, int n_in,
                              void* d_out, int out_size, void* d_ws, size_t ws_size,
                              hipStream_t stream) {
  const float* style_E = (const float*)d_in[0];
  const float* style_S = (const float*)d_in[1];
  const float* trans_E = (const float*)d_in[2];
  const float* trans_S = (const float*)d_in[3];
  const int*   neg_idx = (const int*)d_in[4];

  double* acc = (double*)d_ws;
  float*  Vs  = (float*)((char*)d_ws + 256);

  hipMemsetAsync(d_ws, 0, 256, stream);
  sort_rows<<<ROWS, NTH, 0, stream>>>(style_E, style_S, Vs);
  loss_rows<<<ROWS, NTH, 0, stream>>>(trans_E, trans_S, Vs, neg_idx, acc);
  finalize<<<1, 64, 0, stream>>>(acc, (float*)d_out);
}

// Round 5
// 234.165 us; speedup vs baseline: 1.0574x; 1.0574x over previous
//
#include <hip/hip_runtime.h>

// EFDM loss — reduced form:
//   pos_sum[b]  = sum over (a,p,c,j) of (sortT[a,p,b,c][j] - sortS[a,p,b,c][j])^2
//   neg_sum[b]  = sum over (a,p,k,c,j) of (sortT[a,p,b,c][j] - sortS[a,p,nb(b,k),c][j])^2
//   out = sum_b pos_sum[b]/neg_sum[b]          (the 1/(C*N) mean factors cancel)
//
// Register bitonic sort, 16 elems/thread, 256 thr/row.
//  - sign-negation trick -> all compares static min/max (+cndmask for per-lane side)
//  - lane-xor 1/2 via DPP quad_perm; 4/8 via ds_swizzle; 16/32 via permlane swaps;
//    thread-xor 64/128 via LDS (float4, stride-20 rows, conflict-free)
//  - amdgpu_waves_per_eu(8): VGPR budget 64 (occupancy quantum boundary) so the
//    backend stops squeezing to ~32 VGPR and serializing the unrolled passes
//  - two-phase passes (o[8] batch then minmax batch) force >=8-way ILP

constexpr int N    = 4096;
constexpr int NTH  = 256;
constexpr int CDIM = 128;
constexpr int BDIM = 4;
constexpr int KNEG = 2;
constexpr int ROWS = 4096;
constexpr int HALF = 2048;
constexpr int LSTR = 20;   // floats per thread-row in LDS: 80B, 16B-aligned;
                           // 16B-block stride 5 (mod 8) -> conflict-free b128

__device__ inline unsigned fasu(float x) { return __float_as_uint(x); }
__device__ inline float    usaf(unsigned x) { return __uint_as_float(x); }

__device__ inline void cswap_asc(float& a, float& b) {
  const float lo = fminf(a, b), hi = fmaxf(a, b);
  a = lo; b = hi;
}

// pre-stages k=2,4,8: direction static from local index m
template<int K, int J>
__device__ inline void local_pass(float v[16]) {
  #pragma unroll
  for (int m = 0; m < 16; ++m)
    if ((m & J) == 0) {
      if ((m & K) == 0) cswap_asc(v[m], v[m ^ J]);
      else              cswap_asc(v[m ^ J], v[m]);
    }
}

// ascending in-register tail: j = J, J/2, .., 1
template<int J>
__device__ inline void reg_passes_asc(float v[16]) {
  if constexpr (J >= 1) {
    #pragma unroll
    for (int m = 0; m < 16; ++m)
      if ((m & J) == 0) cswap_asc(v[m], v[m ^ J]);
    reg_passes_asc<(J >> 1)>(v);
  }
}

// DPP quad_perm exchange: 0xB1 = [1,0,3,2] = xor1, 0x4E = [2,3,0,1] = xor2
template<int CTRL>
__device__ inline float dpp_x(float x) {
  const int s = (int)fasu(x);
  return usaf((unsigned)__builtin_amdgcn_update_dpp(s, s, CTRL, 0xF, 0xF, false));
}

// lane-xor TM in {1,2,4,8}: per-lane keep-min = ((t&TM)==0).
// Two-phase in groups of 8: batch exchanges into o[8], then batch min/max —
// forces 8 concurrent exchanges (esp. ds_swizzle latency overlap).
template<int TM>
__device__ inline void pass_small(float v[16], int t) {
  const bool km = ((t & TM) == 0);
  #pragma unroll
  for (int g = 0; g < 16; g += 8) {
    float o[8];
    #pragma unroll
    for (int m = 0; m < 8; ++m) {
      if constexpr (TM == 1)      o[m] = dpp_x<0xB1>(v[g + m]);
      else if constexpr (TM == 2) o[m] = dpp_x<0x4E>(v[g + m]);
      else if constexpr (TM == 4)
        o[m] = usaf((unsigned)__builtin_amdgcn_ds_swizzle((int)fasu(v[g + m]), 0x101F));
      else
        o[m] = usaf((unsigned)__builtin_amdgcn_ds_swizzle((int)fasu(v[g + m]), 0x201F));
    }
    #pragma unroll
    for (int m = 0; m < 8; ++m)
      v[g + m] = km ? fminf(v[g + m], o[m]) : fmaxf(v[g + m], o[m]);
  }
}

// gfx950 permlane swaps: both operands read AND written.
__device__ inline void swap32(float& a, float& b) {
  asm("v_permlane32_swap_b32 %0, %1" : "+v"(a), "+v"(b));
}
__device__ inline void swap16(float& a, float& b) {
  asm("v_permlane16_swap_b32 %0, %1" : "+v"(a), "+v"(b));
}

// lane-xor 16/32 butterfly on element PAIRs, grouped 4 pairs at a time:
// 2 swaps + min + max -> both results, min landing in the (t&TM)==0 lanes.
template<bool IS32>
__device__ inline void pass_perm(float v[16]) {
  #pragma unroll
  for (int g = 0; g < 16; g += 8) {
    float a[4], b[4];
    #pragma unroll
    for (int p = 0; p < 4; ++p) {
      a[p] = v[g + 2*p]; b[p] = v[g + 2*p + 1];
      if constexpr (IS32) swap32(a[p], b[p]); else swap16(a[p], b[p]);
    }
    #pragma unroll
    for (int p = 0; p < 4; ++p) {
      float mn = fminf(a[p], b[p]);
      float mx = fmaxf(a[p], b[p]);
      if constexpr (IS32) swap32(mn, mx); else swap16(mn, mx);
      v[g + 2*p] = mn; v[g + 2*p + 1] = mx;
    }
  }
}

// thread-xor 64/128 via LDS (float4 path); keep decision wave-uniform
template<int TM>
__device__ inline void pass_lds(float v[16], float* buf, int t) {
  __syncthreads();   // protect prior reads of buf
  float4* wp = (float4*)(buf + t * LSTR);
  #pragma unroll
  for (int q = 0; q < 4; ++q)
    wp[q] = make_float4(v[q*4+0], v[q*4+1], v[q*4+2], v[q*4+3]);
  __syncthreads();
  const float4* rp = (const float4*)(buf + (t ^ TM) * LSTR);
  float4 x[4];
  #pragma unroll
  for (int q = 0; q < 4; ++q) x[q] = rp[q];
  if (t & TM) {
    #pragma unroll
    for (int q = 0; q < 4; ++q) {
      v[q*4+0] = fmaxf(v[q*4+0], x[q].x); v[q*4+1] = fmaxf(v[q*4+1], x[q].y);
      v[q*4+2] = fmaxf(v[q*4+2], x[q].z); v[q*4+3] = fmaxf(v[q*4+3], x[q].w);
    }
  } else {
    #pragma unroll
    for (int q = 0; q < 4; ++q) {
      v[q*4+0] = fminf(v[q*4+0], x[q].x); v[q*4+1] = fminf(v[q*4+1], x[q].y);
      v[q*4+2] = fminf(v[q*4+2], x[q].z); v[q*4+3] = fminf(v[q*4+3], x[q].w);
    }
  }
}

template<int K, int J>
__device__ inline void cross_passes(float v[16], float* buf, int t) {
  if constexpr (J >= 16) {
    constexpr int TM = J >> 4;
    if constexpr (TM >= 64)      pass_lds<TM>(v, buf, t);
    else if constexpr (TM == 32) pass_perm<true>(v);
    else if constexpr (TM == 16) pass_perm<false>(v);
    else                         pass_small<TM>(v, t);
    cross_passes<K, (J >> 1)>(v, buf, t);
  }
}

__device__ inline void apply_flip(float v[16], unsigned f) {
  #pragma unroll
  for (int m = 0; m < 16; ++m) v[m] = usaf(fasu(v[m]) ^ f);
}

// one bitonic stage of width K (>=16), in sign-flipped space
template<int K>
__device__ inline void stage_n(float v[16], float* buf, int t, unsigned& cur) {
  const unsigned f = (t & (K >> 4)) ? 0x80000000u : 0u;
  apply_flip(v, f ^ cur);
  cur = f;
  cross_passes<K, (K >> 1)>(v, buf, t);
  reg_passes_asc<8>(v);
}

// full ascending sort of 4096 floats: v[16] per thread, i = t*16+m
__device__ inline void sort4096(float v[16], float* buf, int t) {
  local_pass<2, 1>(v);
  local_pass<4, 2>(v); local_pass<4, 1>(v);
  local_pass<8, 4>(v); local_pass<8, 2>(v); local_pass<8, 1>(v);
  unsigned cur = 0;
  stage_n<16>(v, buf, t, cur);
  stage_n<32>(v, buf, t, cur);
  stage_n<64>(v, buf, t, cur);
  stage_n<128>(v, buf, t, cur);
  stage_n<256>(v, buf, t, cur);
  stage_n<512>(v, buf, t, cur);
  stage_n<1024>(v, buf, t, cur);
  stage_n<2048>(v, buf, t, cur);
  stage_n<4096>(v, buf, t, cur);
  apply_flip(v, cur);   // cur == 0 for all t<256, but keep it general
}

__device__ inline void load16(const float* __restrict__ src, float v[16], int t) {
  const float4* s4 = (const float4*)src;
  #pragma unroll
  for (int q = 0; q < 4; ++q) {
    const float4 x = s4[t * 4 + q];
    v[q * 4 + 0] = x.x; v[q * 4 + 1] = x.y;
    v[q * 4 + 2] = x.z; v[q * 4 + 3] = x.w;
  }
}

__global__ __launch_bounds__(NTH)
__attribute__((amdgpu_waves_per_eu(8)))
void sort_rows(const float* __restrict__ a0, const float* __restrict__ a1,
               float* __restrict__ out) {
  __shared__ float buf[NTH * LSTR];
  const int t = threadIdx.x;
  const int r = blockIdx.x;
  const float* src = (r < HALF) ? a0 + (size_t)r * N
                                : a1 + (size_t)(r - HALF) * N;
  float v[16];
  load16(src, v, t);
  sort4096(v, buf, t);
  float4* d4 = (float4*)(out + (size_t)r * N);
  #pragma unroll
  for (int q = 0; q < 4; ++q)
    d4[t * 4 + q] = make_float4(v[q*4+0], v[q*4+1], v[q*4+2], v[q*4+3]);
}

__global__ __launch_bounds__(NTH)
__attribute__((amdgpu_waves_per_eu(8)))
void loss_rows(const float* __restrict__ t0, const float* __restrict__ t1,
               const float* __restrict__ Vs, const int* __restrict__ neg_idx,
               double* __restrict__ acc) {
  __shared__ float buf[NTH * LSTR];
  __shared__ float red[2][4];
  const int t = threadIdx.x;
  const int r = blockIdx.x;
  const float* src = (r < HALF) ? t0 + (size_t)r * N
                                : t1 + (size_t)(r - HALF) * N;
  float v[16];
  load16(src, v, t);
  sort4096(v, buf, t);

  // r = ((ap)*B + b)*C + c
  const int c  = r & (CDIM - 1);
  const int b  = (r / CDIM) & (BDIM - 1);
  const int ap = r / (CDIM * BDIM);

  float posp = 0.f, negp = 0.f;
  {
    const float4* vp4 = (const float4*)(Vs + (size_t)r * N);
    #pragma unroll
    for (int q = 0; q < 4; ++q) {
      const float4 x = vp4[t * 4 + q];
      float d0 = v[q*4+0] - x.x, d1 = v[q*4+1] - x.y;
      float d2 = v[q*4+2] - x.z, d3 = v[q*4+3] - x.w;
      posp += d0*d0 + d1*d1 + d2*d2 + d3*d3;
    }
  }
  #pragma unroll
  for (int k = 0; k < KNEG; ++k) {
    const int nb = neg_idx[b * KNEG + k];
    const float4* vn4 = (const float4*)(Vs + ((size_t)(ap * BDIM + nb) * CDIM + c) * N);
    #pragma unroll
    for (int q = 0; q < 4; ++q) {
      const float4 x = vn4[t * 4 + q];
      float d0 = v[q*4+0] - x.x, d1 = v[q*4+1] - x.y;
      float d2 = v[q*4+2] - x.z, d3 = v[q*4+3] - x.w;
      negp += d0*d0 + d1*d1 + d2*d2 + d3*d3;
    }
  }

  #pragma unroll
  for (int off = 32; off > 0; off >>= 1) {
    posp += __shfl_down(posp, off, 64);
    negp += __shfl_down(negp, off, 64);
  }
  const int wid = t >> 6, lane = t & 63;
  if (lane == 0) { red[0][wid] = posp; red[1][wid] = negp; }
  __syncthreads();
  if (t == 0) {
    const float pt = red[0][0] + red[0][1] + red[0][2] + red[0][3];
    const float nt = red[1][0] + red[1][1] + red[1][2] + red[1][3];
    atomicAdd(&acc[b], (double)pt);
    atomicAdd(&acc[BDIM + b], (double)nt);
  }
}

__global__ void finalize(const double* __restrict__ acc, float* __restrict__ out) {
  if (threadIdx.x == 0 && blockIdx.x == 0) {
    double s = 0.0;
    for (int b = 0; b < BDIM; ++b) s += acc[b] / acc[BDIM + b];
    out[0] = (float)s;
  }
}

extern "C" void kernel_launch(void* const* d_in, const int* in_sizes, int n_in,
                              void* d_out, int out_size, void* d_ws, size_t ws_size,
                              hipStream_t stream) {
  const float* style_E = (const float*)d_in[0];
  const float* style_S = (const float*)d_in[1];
  const float* trans_E = (const float*)d_in[2];
  const float* trans_S = (const float*)d_in[3];
  const int*   neg_idx = (const int*)d_in[4];

  double* acc = (double*)d_ws;
  float*  Vs  = (float*)((char*)d_ws + 256);

  hipMemsetAsync(d_ws, 0, 256, stream);
  sort_rows<<<ROWS, NTH, 0, stream>>>(style_E, style_S, Vs);
  loss_rows<<<ROWS, NTH, 0, stream>>>(trans_E, trans_S, Vs, neg_idx, acc);
  finalize<<<1, 64, 0, stream>>>(acc, (float*)d_out);
}